// Round 1
// baseline (1108.630 us; speedup 1.0000x reference)
//
#include <hip/hip_runtime.h>

#define N_NODES 100000
#define N_EDGES 20000
#define NNZV    1600000
#define NSEG    (N_EDGES + N_NODES)
#define FIN     128

// ---------------- CSR build ----------------

__global__ void k_count(const int* __restrict__ nidx, const int* __restrict__ eidx,
                        int* __restrict__ cnt) {
  int i = blockIdx.x * blockDim.x + threadIdx.x;
  int st = gridDim.x * blockDim.x;
  for (; i < NNZV; i += st) {
    atomicAdd(&cnt[eidx[i]], 1);
    atomicAdd(&cnt[N_EDGES + nidx[i]], 1);
  }
}

__global__ void k_scan1(const int* __restrict__ cnt, int* __restrict__ incl,
                        int* __restrict__ bsum) {
  __shared__ int s[1024];
  int gid = blockIdx.x * 1024 + threadIdx.x;
  int v = (gid < NSEG) ? cnt[gid] : 0;
  s[threadIdx.x] = v;
  __syncthreads();
  for (int d = 1; d < 1024; d <<= 1) {
    int t = (threadIdx.x >= d) ? s[threadIdx.x - d] : 0;
    __syncthreads();
    s[threadIdx.x] += t;
    __syncthreads();
  }
  if (gid < NSEG) incl[gid] = s[threadIdx.x];
  if (threadIdx.x == 1023) bsum[blockIdx.x] = s[1023];
}

__global__ void k_scan2(int* __restrict__ bsum, int nb) {
  __shared__ int s[128];
  int v = (threadIdx.x < nb) ? bsum[threadIdx.x] : 0;
  s[threadIdx.x] = v;
  __syncthreads();
  for (int d = 1; d < 128; d <<= 1) {
    int t = (threadIdx.x >= (unsigned)d) ? s[threadIdx.x - d] : 0;
    __syncthreads();
    s[threadIdx.x] += t;
    __syncthreads();
  }
  if (threadIdx.x < nb) bsum[threadIdx.x] = s[threadIdx.x] - v;  // exclusive
}

__global__ void k_scan3(int* __restrict__ off, const int* __restrict__ cnt,
                        const int* __restrict__ bsum) {
  int gid = blockIdx.x * 1024 + threadIdx.x;
  if (gid < NSEG) off[gid] = off[gid] - cnt[gid] + bsum[blockIdx.x];
}

__global__ void k_fill(const int* __restrict__ nidx, const int* __restrict__ eidx,
                       const int* __restrict__ off, int* __restrict__ cur,
                       int* __restrict__ csr) {
  int i = blockIdx.x * blockDim.x + threadIdx.x;
  int st = gridDim.x * blockDim.x;
  for (; i < NNZV; i += st) {
    int e = eidx[i], n = nidx[i];
    int pe = atomicAdd(&cur[e], 1);
    csr[off[e] + pe] = n;
    int pn = atomicAdd(&cur[N_EDGES + n], 1);
    csr[off[N_EDGES + n] + pn] = e;
  }
}

// ---------------- node -> edge (raw features, apply B = 1/|e|) ----------------

__global__ __launch_bounds__(256) void k_passA(const float* __restrict__ xin,
                                               const int* __restrict__ csr,
                                               const int* __restrict__ off,
                                               const int* __restrict__ cnt,
                                               float* __restrict__ ebuf) {
  int wave = (blockIdx.x * blockDim.x + threadIdx.x) >> 6;
  int lane = threadIdx.x & 63;
  if (wave >= N_EDGES) return;
  int beg = off[wave];
  int m   = cnt[wave];
  int c = lane * 2;
  float2 acc = make_float2(0.f, 0.f);
  int idxv = 0;
  for (int j = 0; j < m; ++j) {
    int jm = j & 63;
    if (jm == 0) idxv = ((j + lane) < m) ? csr[beg + j + lane] : 0;
    int node = __shfl(idxv, jm);
    float2 v = *reinterpret_cast<const float2*>(xin + (size_t)node * FIN + c);
    acc.x += v.x; acc.y += v.y;
  }
  float binv = (m > 0) ? (1.f / (float)m) : 0.f;
  acc.x *= binv; acc.y *= binv;
  *reinterpret_cast<float2*>(ebuf + (size_t)wave * FIN + c) = acc;
}

// ---------------- edge-level GEMM: Out[20000][FOUT] = A[20000][128] @ W[128][FOUT] ----------------

template <int FOUT>
__global__ void k_gemm(const float* __restrict__ A, const float* __restrict__ W,
                       float* __restrict__ Out) {
  constexpr int CT = FOUT / 8;   // threads along columns
  constexpr int NT = CT * 16;    // block threads
  __shared__ float As[64][33];
  __shared__ float Ws[32][FOUT];
  int tid = threadIdx.x;
  int tx = tid % CT, ty = tid / CT;
  int row0 = blockIdx.x * 64;
  float acc[4][8];
#pragma unroll
  for (int i = 0; i < 4; ++i)
#pragma unroll
    for (int j = 0; j < 8; ++j) acc[i][j] = 0.f;

  for (int kc = 0; kc < FIN; kc += 32) {
    for (int i = tid; i < 64 * 32; i += NT) {
      int r = i >> 5, k = i & 31;
      int gr = row0 + r;
      As[r][k] = (gr < N_EDGES) ? A[(size_t)gr * FIN + kc + k] : 0.f;
    }
    for (int i = tid; i < 32 * FOUT; i += NT) {
      int k = i / FOUT, cc = i % FOUT;
      Ws[k][cc] = W[(size_t)(kc + k) * FOUT + cc];
    }
    __syncthreads();
#pragma unroll
    for (int k = 0; k < 32; ++k) {
      float a[4];
#pragma unroll
      for (int i = 0; i < 4; ++i) a[i] = As[ty * 4 + i][k];
      float w[8];
#pragma unroll
      for (int j = 0; j < 8; ++j) w[j] = Ws[k][tx * 8 + j];
#pragma unroll
      for (int i = 0; i < 4; ++i)
#pragma unroll
        for (int j = 0; j < 8; ++j) acc[i][j] += a[i] * w[j];
    }
    __syncthreads();
  }
#pragma unroll
  for (int i = 0; i < 4; ++i) {
    int gr = row0 + ty * 4 + i;
    if (gr < N_EDGES) {
#pragma unroll
      for (int j = 0; j < 8; ++j)
        Out[(size_t)gr * FOUT + tx * 8 + j] = acc[i][j];
    }
  }
}

// ---------------- edge -> node (apply D = 1/deg, +bias, optional relu) ----------------

template <int FOUT, bool RELU>
__global__ __launch_bounds__(256) void k_passB(const float* __restrict__ efeat,
                                               const int* __restrict__ csr,
                                               const int* __restrict__ off,
                                               const int* __restrict__ cnt,
                                               const float* __restrict__ bias,
                                               float* __restrict__ out) {
  int wave = (blockIdx.x * blockDim.x + threadIdx.x) >> 6;
  int lane = threadIdx.x & 63;
  if (wave >= N_NODES) return;
  int beg = off[N_EDGES + wave];
  int m   = cnt[N_EDGES + wave];
  if constexpr (FOUT == 128) {
    int c = lane * 2;
    float2 acc = make_float2(0.f, 0.f);
    int idxv = 0;
    for (int j = 0; j < m; ++j) {
      int jm = j & 63;
      if (jm == 0) idxv = ((j + lane) < m) ? csr[beg + j + lane] : 0;
      int e = __shfl(idxv, jm);
      float2 v = *reinterpret_cast<const float2*>(efeat + (size_t)e * FOUT + c);
      acc.x += v.x; acc.y += v.y;
    }
    float dinv = (m > 0) ? (1.f / (float)m) : 0.f;
    float ox = acc.x * dinv + bias[c];
    float oy = acc.y * dinv + bias[c + 1];
    if (RELU) { ox = fmaxf(ox, 0.f); oy = fmaxf(oy, 0.f); }
    *reinterpret_cast<float2*>(out + (size_t)wave * FOUT + c) = make_float2(ox, oy);
  } else {
    int c = lane;
    float acc = 0.f;
    int idxv = 0;
    for (int j = 0; j < m; ++j) {
      int jm = j & 63;
      if (jm == 0) idxv = ((j + lane) < m) ? csr[beg + j + lane] : 0;
      int e = __shfl(idxv, jm);
      acc += efeat[(size_t)e * FOUT + c];
    }
    float dinv = (m > 0) ? (1.f / (float)m) : 0.f;
    float o = acc * dinv + bias[c];
    if (RELU) o = fmaxf(o, 0.f);
    out[(size_t)wave * FOUT + c] = o;
  }
}

// ---------------- launch ----------------

extern "C" void kernel_launch(void* const* d_in, const int* in_sizes, int n_in,
                              void* d_out, int out_size, void* d_ws, size_t ws_size,
                              hipStream_t stream) {
  const float* x  = (const float*)d_in[0];
  const float* W1 = (const float*)d_in[1];
  const float* b1 = (const float*)d_in[2];
  const float* W2 = (const float*)d_in[3];
  const float* b2 = (const float*)d_in[4];
  const float* W3 = (const float*)d_in[5];
  const float* b3 = (const float*)d_in[6];
  const int* nidx = (const int*)d_in[7];
  const int* eidx = (const int*)d_in[8];

  // workspace layout (bytes)
  const size_t OFF_CNT  = 0;          // int[120000]
  const size_t OFF_OFF  = 480000;     // int[120000]
  const size_t OFF_CUR  = 960000;     // int[120000]
  const size_t OFF_BSUM = 1440000;    // int[128]
  const size_t OFF_CSR  = 1441792;    // int[3200000]
  const size_t OFF_EB   = 14241792;   // float[20000*128]
  const size_t OFF_EB2  = 24481792;   // float[20000*128]
  const size_t OFF_H    = 34721792;   // float[100000*128]
  const size_t NEEDED   = 85921792;
  if (ws_size < NEEDED) return;  // fail validation visibly rather than corrupt

  char* ws = (char*)d_ws;
  int*   cnt   = (int*)(ws + OFF_CNT);
  int*   off   = (int*)(ws + OFF_OFF);
  int*   cur   = (int*)(ws + OFF_CUR);
  int*   bsum  = (int*)(ws + OFF_BSUM);
  int*   csr   = (int*)(ws + OFF_CSR);
  float* ebuf  = (float*)(ws + OFF_EB);
  float* ebuf2 = (float*)(ws + OFF_EB2);
  float* h     = (float*)(ws + OFF_H);
  float* out   = (float*)d_out;

  hipMemsetAsync(ws, 0, OFF_BSUM + 512, stream);  // cnt, off, cur, bsum

  k_count<<<1024, 256, 0, stream>>>(nidx, eidx, cnt);
  const int nb = (NSEG + 1023) / 1024;  // 118
  k_scan1<<<nb, 1024, 0, stream>>>(cnt, off, bsum);
  k_scan2<<<1, 128, 0, stream>>>(bsum, nb);
  k_scan3<<<nb, 1024, 0, stream>>>(off, cnt, bsum);
  k_fill<<<1024, 256, 0, stream>>>(nidx, eidx, off, cur, csr);

  const int BLK_A = (N_EDGES * 64 + 255) / 256;   // 5000
  const int BLK_B = (N_NODES * 64 + 255) / 256;   // 25000
  const int BLK_G = (N_EDGES + 63) / 64;          // 313

  // layer 1: x -> h (relu)
  k_passA<<<BLK_A, 256, 0, stream>>>(x, csr, off, cnt, ebuf);
  k_gemm<128><<<BLK_G, 256, 0, stream>>>(ebuf, W1, ebuf2);
  k_passB<128, true><<<BLK_B, 256, 0, stream>>>(ebuf2, csr, off, cnt, b1, h);

  // layer 2: h -> h (relu)
  k_passA<<<BLK_A, 256, 0, stream>>>(h, csr, off, cnt, ebuf);
  k_gemm<128><<<BLK_G, 256, 0, stream>>>(ebuf, W2, ebuf2);
  k_passB<128, true><<<BLK_B, 256, 0, stream>>>(ebuf2, csr, off, cnt, b2, h);

  // layer 3: h -> out (no relu, FOUT=64)
  k_passA<<<BLK_A, 256, 0, stream>>>(h, csr, off, cnt, ebuf);
  k_gemm<64><<<BLK_G, 128, 0, stream>>>(ebuf, W3, ebuf2);
  k_passB<64, false><<<BLK_B, 256, 0, stream>>>(ebuf2, csr, off, cnt, b3, out);
}

// Round 2
// 1095.590 us; speedup vs baseline: 1.0119x; 1.0119x over previous
//
#include <hip/hip_runtime.h>

#define N_NODES 100000
#define N_EDGES 20000
#define NNZV    1600000
#define NSEG    (N_EDGES + N_NODES)
#define FIN     128
#define NPART   8
#define E_PER_P (N_EDGES / NPART)   // 2500
#define N_PER_P (N_NODES / NPART)   // 12500

// ---------------- CSR build (destination-partitioned by XCD) ----------------
// Partition p = blockIdx.x % 8 only touches cnt/cur/csr entries in its own
// destination range, so (assuming blockIdx%8 ~ XCD round-robin) every CSR
// cache line is written by a single XCD and stays L2-resident until fully
// assembled -> ~1x write traffic instead of 16x partial-line writebacks.

__global__ void k_count(const int* __restrict__ nidx, const int* __restrict__ eidx,
                        int* __restrict__ cnt) {
  int p = blockIdx.x & (NPART - 1);
  int e_lo = p * E_PER_P, e_hi = e_lo + E_PER_P;
  int n_lo = p * N_PER_P, n_hi = n_lo + N_PER_P;
  int i = (blockIdx.x >> 3) * blockDim.x + threadIdx.x;
  int st = (gridDim.x >> 3) * blockDim.x;
  for (; i < NNZV; i += st) {
    int e = eidx[i];
    int n = nidx[i];
    if (e >= e_lo && e < e_hi) atomicAdd(&cnt[e], 1);
    if (n >= n_lo && n < n_hi) atomicAdd(&cnt[N_EDGES + n], 1);
  }
}

__global__ void k_scan1(const int* __restrict__ cnt, int* __restrict__ incl,
                        int* __restrict__ bsum) {
  __shared__ int s[1024];
  int gid = blockIdx.x * 1024 + threadIdx.x;
  int v = (gid < NSEG) ? cnt[gid] : 0;
  s[threadIdx.x] = v;
  __syncthreads();
  for (int d = 1; d < 1024; d <<= 1) {
    int t = (threadIdx.x >= d) ? s[threadIdx.x - d] : 0;
    __syncthreads();
    s[threadIdx.x] += t;
    __syncthreads();
  }
  if (gid < NSEG) incl[gid] = s[threadIdx.x];
  if (threadIdx.x == 1023) bsum[blockIdx.x] = s[1023];
}

__global__ void k_scan2(int* __restrict__ bsum, int nb) {
  __shared__ int s[128];
  int v = (threadIdx.x < nb) ? bsum[threadIdx.x] : 0;
  s[threadIdx.x] = v;
  __syncthreads();
  for (int d = 1; d < 128; d <<= 1) {
    int t = (threadIdx.x >= (unsigned)d) ? s[threadIdx.x - d] : 0;
    __syncthreads();
    s[threadIdx.x] += t;
    __syncthreads();
  }
  if (threadIdx.x < nb) bsum[threadIdx.x] = s[threadIdx.x] - v;  // exclusive
}

__global__ void k_scan3(int* __restrict__ off, const int* __restrict__ cnt,
                        const int* __restrict__ bsum) {
  int gid = blockIdx.x * 1024 + threadIdx.x;
  if (gid < NSEG) off[gid] = off[gid] - cnt[gid] + bsum[blockIdx.x];
}

__global__ void k_fill(const int* __restrict__ nidx, const int* __restrict__ eidx,
                       const int* __restrict__ off, int* __restrict__ cur,
                       int* __restrict__ csr) {
  int p = blockIdx.x & (NPART - 1);
  int e_lo = p * E_PER_P, e_hi = e_lo + E_PER_P;
  int n_lo = p * N_PER_P, n_hi = n_lo + N_PER_P;
  int i = (blockIdx.x >> 3) * blockDim.x + threadIdx.x;
  int st = (gridDim.x >> 3) * blockDim.x;
  for (; i < NNZV; i += st) {
    int e = eidx[i], n = nidx[i];
    if (e >= e_lo && e < e_hi) {
      int pe = atomicAdd(&cur[e], 1);
      csr[off[e] + pe] = n;
    }
    if (n >= n_lo && n < n_hi) {
      int pn = atomicAdd(&cur[N_EDGES + n], 1);
      csr[off[N_EDGES + n] + pn] = e;
    }
  }
}

// ---------------- node -> edge (raw features, apply B = 1/|e|) ----------------

__global__ __launch_bounds__(256) void k_passA(const float* __restrict__ xin,
                                               const int* __restrict__ csr,
                                               const int* __restrict__ off,
                                               const int* __restrict__ cnt,
                                               float* __restrict__ ebuf) {
  int wave = (blockIdx.x * blockDim.x + threadIdx.x) >> 6;
  int lane = threadIdx.x & 63;
  if (wave >= N_EDGES) return;
  int beg = off[wave];
  int m   = cnt[wave];
  int c = lane * 2;
  float2 acc = make_float2(0.f, 0.f);
  int idxv = 0;
  for (int j = 0; j < m; ++j) {
    int jm = j & 63;
    if (jm == 0) idxv = ((j + lane) < m) ? csr[beg + j + lane] : 0;
    int node = __shfl(idxv, jm);
    float2 v = *reinterpret_cast<const float2*>(xin + (size_t)node * FIN + c);
    acc.x += v.x; acc.y += v.y;
  }
  float binv = (m > 0) ? (1.f / (float)m) : 0.f;
  acc.x *= binv; acc.y *= binv;
  *reinterpret_cast<float2*>(ebuf + (size_t)wave * FIN + c) = acc;
}

// ---------------- edge-level GEMM: Out[20000][FOUT] = A[20000][128] @ W[128][FOUT] ----------------

template <int FOUT>
__global__ void k_gemm(const float* __restrict__ A, const float* __restrict__ W,
                       float* __restrict__ Out) {
  constexpr int CT = FOUT / 8;   // threads along columns
  constexpr int NT = CT * 16;    // block threads
  __shared__ float As[64][33];
  __shared__ float Ws[32][FOUT];
  int tid = threadIdx.x;
  int tx = tid % CT, ty = tid / CT;
  int row0 = blockIdx.x * 64;
  float acc[4][8];
#pragma unroll
  for (int i = 0; i < 4; ++i)
#pragma unroll
    for (int j = 0; j < 8; ++j) acc[i][j] = 0.f;

  for (int kc = 0; kc < FIN; kc += 32) {
    for (int i = tid; i < 64 * 32; i += NT) {
      int r = i >> 5, k = i & 31;
      int gr = row0 + r;
      As[r][k] = (gr < N_EDGES) ? A[(size_t)gr * FIN + kc + k] : 0.f;
    }
    for (int i = tid; i < 32 * FOUT; i += NT) {
      int k = i / FOUT, cc = i % FOUT;
      Ws[k][cc] = W[(size_t)(kc + k) * FOUT + cc];
    }
    __syncthreads();
#pragma unroll
    for (int k = 0; k < 32; ++k) {
      float a[4];
#pragma unroll
      for (int i = 0; i < 4; ++i) a[i] = As[ty * 4 + i][k];
      float w[8];
#pragma unroll
      for (int j = 0; j < 8; ++j) w[j] = Ws[k][tx * 8 + j];
#pragma unroll
      for (int i = 0; i < 4; ++i)
#pragma unroll
        for (int j = 0; j < 8; ++j) acc[i][j] += a[i] * w[j];
    }
    __syncthreads();
  }
#pragma unroll
  for (int i = 0; i < 4; ++i) {
    int gr = row0 + ty * 4 + i;
    if (gr < N_EDGES) {
#pragma unroll
      for (int j = 0; j < 8; ++j)
        Out[(size_t)gr * FOUT + tx * 8 + j] = acc[i][j];
    }
  }
}

// ---------------- edge -> node (apply D = 1/deg, +bias, optional relu) ----------------

template <int FOUT, bool RELU>
__global__ __launch_bounds__(256) void k_passB(const float* __restrict__ efeat,
                                               const int* __restrict__ csr,
                                               const int* __restrict__ off,
                                               const int* __restrict__ cnt,
                                               const float* __restrict__ bias,
                                               float* __restrict__ out) {
  int wave = (blockIdx.x * blockDim.x + threadIdx.x) >> 6;
  int lane = threadIdx.x & 63;
  if (wave >= N_NODES) return;
  int beg = off[N_EDGES + wave];
  int m   = cnt[N_EDGES + wave];
  if constexpr (FOUT == 128) {
    int c = lane * 2;
    float2 acc = make_float2(0.f, 0.f);
    int idxv = 0;
    for (int j = 0; j < m; ++j) {
      int jm = j & 63;
      if (jm == 0) idxv = ((j + lane) < m) ? csr[beg + j + lane] : 0;
      int e = __shfl(idxv, jm);
      float2 v = *reinterpret_cast<const float2*>(efeat + (size_t)e * FOUT + c);
      acc.x += v.x; acc.y += v.y;
    }
    float dinv = (m > 0) ? (1.f / (float)m) : 0.f;
    float ox = acc.x * dinv + bias[c];
    float oy = acc.y * dinv + bias[c + 1];
    if (RELU) { ox = fmaxf(ox, 0.f); oy = fmaxf(oy, 0.f); }
    *reinterpret_cast<float2*>(out + (size_t)wave * FOUT + c) = make_float2(ox, oy);
  } else {
    int c = lane;
    float acc = 0.f;
    int idxv = 0;
    for (int j = 0; j < m; ++j) {
      int jm = j & 63;
      if (jm == 0) idxv = ((j + lane) < m) ? csr[beg + j + lane] : 0;
      int e = __shfl(idxv, jm);
      acc += efeat[(size_t)e * FOUT + c];
    }
    float dinv = (m > 0) ? (1.f / (float)m) : 0.f;
    float o = acc * dinv + bias[c];
    if (RELU) o = fmaxf(o, 0.f);
    out[(size_t)wave * FOUT + c] = o;
  }
}

// ---------------- launch ----------------

extern "C" void kernel_launch(void* const* d_in, const int* in_sizes, int n_in,
                              void* d_out, int out_size, void* d_ws, size_t ws_size,
                              hipStream_t stream) {
  const float* x  = (const float*)d_in[0];
  const float* W1 = (const float*)d_in[1];
  const float* b1 = (const float*)d_in[2];
  const float* W2 = (const float*)d_in[3];
  const float* b2 = (const float*)d_in[4];
  const float* W3 = (const float*)d_in[5];
  const float* b3 = (const float*)d_in[6];
  const int* nidx = (const int*)d_in[7];
  const int* eidx = (const int*)d_in[8];

  // workspace layout (bytes)
  const size_t OFF_CNT  = 0;          // int[120000]
  const size_t OFF_OFF  = 480000;     // int[120000]
  const size_t OFF_CUR  = 960000;     // int[120000]
  const size_t OFF_BSUM = 1440000;    // int[128]
  const size_t OFF_CSR  = 1441792;    // int[3200000]
  const size_t OFF_EB   = 14241792;   // float[20000*128]
  const size_t OFF_EB2  = 24481792;   // float[20000*128]
  const size_t OFF_H    = 34721792;   // float[100000*128]
  const size_t NEEDED   = 85921792;
  if (ws_size < NEEDED) return;  // fail validation visibly rather than corrupt

  char* ws = (char*)d_ws;
  int*   cnt   = (int*)(ws + OFF_CNT);
  int*   off   = (int*)(ws + OFF_OFF);
  int*   cur   = (int*)(ws + OFF_CUR);
  int*   bsum  = (int*)(ws + OFF_BSUM);
  int*   csr   = (int*)(ws + OFF_CSR);
  float* ebuf  = (float*)(ws + OFF_EB);
  float* ebuf2 = (float*)(ws + OFF_EB2);
  float* h     = (float*)(ws + OFF_H);
  float* out   = (float*)d_out;

  hipMemsetAsync(ws, 0, OFF_BSUM + 512, stream);  // cnt, off, cur, bsum

  k_count<<<1024, 256, 0, stream>>>(nidx, eidx, cnt);
  const int nb = (NSEG + 1023) / 1024;  // 118
  k_scan1<<<nb, 1024, 0, stream>>>(cnt, off, bsum);
  k_scan2<<<1, 128, 0, stream>>>(bsum, nb);
  k_scan3<<<nb, 1024, 0, stream>>>(off, cnt, bsum);
  k_fill<<<1024, 256, 0, stream>>>(nidx, eidx, off, cur, csr);

  const int BLK_A = (N_EDGES * 64 + 255) / 256;   // 5000
  const int BLK_B = (N_NODES * 64 + 255) / 256;   // 25000
  const int BLK_G = (N_EDGES + 63) / 64;          // 313

  // layer 1: x -> h (relu)
  k_passA<<<BLK_A, 256, 0, stream>>>(x, csr, off, cnt, ebuf);
  k_gemm<128><<<BLK_G, 256, 0, stream>>>(ebuf, W1, ebuf2);
  k_passB<128, true><<<BLK_B, 256, 0, stream>>>(ebuf2, csr, off, cnt, b1, h);

  // layer 2: h -> h (relu)
  k_passA<<<BLK_A, 256, 0, stream>>>(h, csr, off, cnt, ebuf);
  k_gemm<128><<<BLK_G, 256, 0, stream>>>(ebuf, W2, ebuf2);
  k_passB<128, true><<<BLK_B, 256, 0, stream>>>(ebuf2, csr, off, cnt, b2, h);

  // layer 3: h -> out (no relu, FOUT=64)
  k_passA<<<BLK_A, 256, 0, stream>>>(h, csr, off, cnt, ebuf);
  k_gemm<64><<<BLK_G, 128, 0, stream>>>(ebuf, W3, ebuf2);
  k_passB<64, false><<<BLK_B, 256, 0, stream>>>(ebuf2, csr, off, cnt, b3, out);
}